// Round 14
// baseline (158.831 us; speedup 1.0000x reference)
//
#include <hip/hip_runtime.h>
#include <hip/hip_bf16.h>
#include <cstdint>
#include <cstddef>

typedef __hip_bfloat16 bf16;
typedef __attribute__((ext_vector_type(8))) short bf8v;   // 8 bf16 MFMA A/B frag
typedef __attribute__((ext_vector_type(4))) float f4v;    // MFMA C/D frag
typedef __attribute__((ext_vector_type(4))) short s4v;
typedef __attribute__((ext_vector_type(8))) short s8v;

#define DEV static __device__ __forceinline__

DEV float siluf(float v){ return v / (1.0f + __expf(-v)); }
DEV short bfs(float f){ bf16 h = __float2bfloat16(f); return __builtin_bit_cast(short, h); }
DEV float b2f(short s){ return __builtin_bit_cast(float, (unsigned)((unsigned short)s) << 16); }

DEV void gload16(const bf16* g, bf16* l){
  __builtin_amdgcn_global_load_lds((const __attribute__((address_space(1))) void*)g,
                                   (__attribute__((address_space(3))) void*)l, 16, 0, 0);
}

// ---------------- bt-GEMM core, BK=64: C(MxN)=A*Bt^T. BM=128, BN=128, 256 thr.
DEV void gemm_core128(const bf16* __restrict__ A, int lda,
                      const bf16* __restrict__ Bt, int ldb,
                      int K, bf16* As, bf16* Bs, f4v (&acc)[4][4],
                      int bm, int bn, int k0)
{
  const int t = threadIdx.x, w = t>>6, l = t&63;
  const int wr = w>>1, wc = w&1, lr = l&15, kb = l>>4;
#pragma unroll
  for (int i=0;i<4;i++)
#pragma unroll
    for (int j=0;j<4;j++) acc[i][j] = (f4v)(0.0f);

  for (int kt=k0; kt<k0+K; kt+=64){
    __syncthreads();
#pragma unroll
    for (int s=0;s<2;s++){
#pragma unroll
      for (int i=0;i<2;i++){
        int lin = t + i*256;
        gload16(A + (size_t)(bm + (lin>>2))*lda + kt + s*32 + (lin&3)*8,
                As + s*4096 + (size_t)(w*64 + i*256)*8);
      }
#pragma unroll
      for (int i=0;i<2;i++){
        int lin = t + i*256;
        gload16(Bt + (size_t)(bn + (lin>>2))*ldb + kt + s*32 + (lin&3)*8,
                Bs + s*4096 + (size_t)(w*64 + i*256)*8);
      }
    }
    __syncthreads();
#pragma unroll
    for (int s=0;s<2;s++){
      bf8v af[4], bfr[4];
#pragma unroll
      for (int i=0;i<4;i++) af[i]  = *(const bf8v*)(As + s*4096 + (wr*64 + i*16 + lr)*32 + kb*8);
#pragma unroll
      for (int j=0;j<4;j++) bfr[j] = *(const bf8v*)(Bs + s*4096 + (wc*64 + j*16 + lr)*32 + kb*8);
#pragma unroll
      for (int i=0;i<4;i++)
#pragma unroll
        for (int j=0;j<4;j++)
          acc[i][j] = __builtin_amdgcn_mfma_f32_16x16x32_bf16(af[i], bfr[j], acc[i][j], 0,0,0);
    }
  }
}

#define EPI_LOOP(...) { \
  const int t_=threadIdx.x, w_=t_>>6, l_=t_&63; \
  const int wr_=w_>>1, wc_=w_&1, lr_=l_&15, kb_=l_>>4; \
  _Pragma("unroll") for (int i_=0;i_<4;i_++) \
  _Pragma("unroll") for (int j_=0;j_<4;j_++) \
  _Pragma("unroll") for (int r_=0;r_<4;r_++){ \
    const int row = bm + wr_*64 + i_*16 + kb_*4 + r_; \
    const int col = bn + wc_*64 + j_*16 + lr_; \
    float v = acc[i_][j_][r_]; \
    __VA_ARGS__; \
  } }

// ---------------- stage-1: uvqk transpose + input rmsnorm (gemm1's inputs only)
__global__ __launch_bounds__(256) void k_pre(
    const float* __restrict__ x, const float* __restrict__ uvqk,
    bf16* __restrict__ xn, bf16* __restrict__ uvqkT){
  __shared__ float tile[32][33];
  __shared__ float sbuf[16];
  int id = blockIdx.x;
  if (id < 1536){
    // uvqk (512 x 3072) -> uvqkT (3072 x 512)
    const int nbx = 96;
    const int c0 = (id % nbx)*32, r0 = (id / nbx)*32;
    const int tx = threadIdx.x & 31, ty = threadIdx.x >> 5;
#pragma unroll
    for (int i=0;i<32;i+=8) tile[ty+i][tx] = uvqk[(size_t)(r0+ty+i)*3072 + (c0+tx)];
    __syncthreads();
#pragma unroll
    for (int i=0;i<32;i+=8) uvqkT[(size_t)(c0+ty+i)*512 + (r0+tx)] = __float2bfloat16(tile[tx][ty+i]);
  } else {
    // input rmsnorm — bit-identical to round-9 k_rmsnorm (128 active threads, float4)
    const size_t row = id - 1536;
    const int t = threadIdx.x;
    if (t >= 128) return;
    const float4 v = ((const float4*)(x + row*512))[t];
    float ss = v.x*v.x + v.y*v.y + v.z*v.z + v.w*v.w;
#pragma unroll
    for (int o=32;o>0;o>>=1) ss += __shfl_down(ss, o);
    const int ln = t & 63, wv = t >> 6;
    if (ln==0) sbuf[wv] = ss;
    __syncthreads();
    if (t==0) sbuf[8] = rsqrtf((sbuf[0]+sbuf[1])*(1.0f/512.0f) + 1e-6f);
    __syncthreads();
    const float r = sbuf[8];
    s4v o; o[0]=bfs(v.x*r); o[1]=bfs(v.y*r); o[2]=bfs(v.z*r); o[3]=bfs(v.w*r);
    ((s4v*)(xn + row*512))[t] = o;
  }
}

// ---------------- stage-2: gemm1 (ids 0..767) + late weight transposes (768..4607)
//                           + bias matrices (4608..13823), one dispatch.
__global__ __launch_bounds__(256) void k_gemm1x(
    const bf16* __restrict__ xn,   const bf16* __restrict__ uvqkT,
    const int* __restrict__ ts,    const float* __restrict__ pos_w,
    const float* __restrict__ ts_w,
    const float* __restrict__ W0,  const float* __restrict__ W1,
    const float* __restrict__ W3,  const float* __restrict__ W2,
    bf16* __restrict__ mm,  bf16* __restrict__ vT,
    bf16* __restrict__ W0T, bf16* __restrict__ W13T, bf16* __restrict__ W2T,
    bf16* __restrict__ Apos, bf16* __restrict__ Ats){
  __shared__ __align__(16) char smem_raw[32768];
  int id = blockIdx.x;
  if (id < 768){
    // mm = silu(xn @ uvqk); v-cols (1536..2048) written transposed into vT
    bf16* As = (bf16*)smem_raw;            // [2][128][32] 16KB
    bf16* Bs = (bf16*)(smem_raw + 16384);  // 16KB
    f4v acc[4][4];
    const int bm = (id & 31)*128, bn = (id >> 5)*128;
    gemm_core128(xn, 512, uvqkT, 512, 512, As, Bs, acc, bm, bn, 0);
    const int t=threadIdx.x, w=t>>6, l=t&63;
    const int wr=w>>1, wc=w&1, lr=l&15, kb=l>>4;
    const bool isv = (bn >= 1536) && (bn < 2048);
#pragma unroll
    for (int i=0;i<4;i++)
#pragma unroll
    for (int j=0;j<4;j++){
      const int row0 = bm + wr*64 + i*16 + kb*4;
      const int col  = bn + wc*64 + j*16 + lr;
      if (!isv){
#pragma unroll
        for (int r=0;r<4;r++)
          mm[(size_t)(row0+r)*3072 + col] = __float2bfloat16(siluf(acc[i][j][r]));
      } else {
        s4v p;
#pragma unroll
        for (int r=0;r<4;r++) p[r] = bfs(siluf(acc[i][j][r]));
        const int b = row0 >> 9, m = row0 & 511;
        *(s4v*)(vT + ((size_t)b*512 + (col-1536))*512 + m) = p;   // vT[b][vcol][m]
      }
    }
  } else if (id < 4608){
    // late weight transposes (not needed until w0/w13f/w2)
    int id2 = id - 768;
    const float* src; bf16* dst; int R, C;
    if      (id2 < 768){             src=W0; dst=W0T;                    R=1536; C=512;  }
    else if (id2 < 1792){ id2-=768;  src=W1; dst=W13T;                   R=512;  C=2048; }
    else if (id2 < 2816){ id2-=1792; src=W3; dst=W13T+(size_t)2048*512;  R=512;  C=2048; }
    else                { id2-=2816; src=W2; dst=W2T;                    R=2048; C=512;  }
    float (*tile)[33] = (float(*)[33])smem_raw;
    const int nbx = C >> 5;
    const int c0 = (id2 % nbx)*32, r0 = (id2 / nbx)*32;
    const int tx = threadIdx.x & 31, ty = threadIdx.x >> 5;
#pragma unroll
    for (int i=0;i<32;i+=8) tile[ty+i][tx] = src[(size_t)(r0+ty+i)*C + (c0+tx)];
    __syncthreads();
#pragma unroll
    for (int i=0;i<32;i+=8) dst[(size_t)(c0+ty+i)*R + (r0+tx)] = __float2bfloat16(tile[tx][ty+i]);
  } else {
    // bias matrices (not needed until k_attn)
    int id2 = id - 4608;
    const int mblk = id2 & 1, n = (id2>>1)&511, z = id2>>10;
    if (mblk*256 > n) return;                 // above diagonal: zero & unread
    const int m = mblk*256 + threadIdx.x;
    if (z == 0){
      float v = (n >= m) ? pos_w[n - m + 1023] : 0.f;
      Apos[(size_t)n*512 + m] = __float2bfloat16(v);
    } else {
      const int b = z-1;
      int dt = ts[b*1024 + n] - ts[b*1024 + m];
      float ad = (float)(dt < 0 ? -dt : dt);
      int bucket = (int)floorf(logf(ad + 1.0f));
      bucket = bucket < 0 ? 0 : (bucket > 127 ? 127 : bucket);
      float v = (n >= m) ? ts_w[bucket] : 0.f;
      Ats[((size_t)b*512 + n)*512 + m] = __float2bfloat16(v);
    }
  }
}

// merged attention: ids 0..255 = fused lat channel (flash-style), 256..511 = pos/ts PV GEMMs.
// bm mapped heavy-first (3-(id&3)) for better tail packing.
__global__ __launch_bounds__(256) void k_attn(const bf16* __restrict__ mm,
                                              const bf16* __restrict__ vT,
                                              const bf16* __restrict__ Apos,
                                              const bf16* __restrict__ Ats,
                                              bf16* __restrict__ comb){
  __shared__ __align__(16) bf16 smem[40960];   // 80 KB carved per branch
  const int id = blockIdx.x;
  const int t = threadIdx.x, w = t>>6, l = t&63;
  const int wr = w>>1, wc = w&1, lr = l&15, kb = l>>4;

  if (id < 256){
    // ---- lat channel: O[128x64] = sum_bn tril(silu(Q Kt)/N) @ V ----
    bf16* Qs = smem;            // [2][128][32] 16KB
    bf16* Ks = smem + 8192;     // 16KB
    bf16* Vs = smem + 16384;    // [4][64][32] 16KB
    bf16* Ss = smem + 24576;    // [4][128][32] 32KB
    const int bm = (3-(id & 3))*128;
    const int z = id >> 2, b = z>>3, h = z&7;
    const bf16* Qg = mm + (size_t)b*512*3072 + 2048 + h*64;
    const bf16* Kg = mm + (size_t)b*512*3072 + 2560 + h*64;
    const bf16* Vg = vT + ((size_t)b*512 + h*64)*512;
    f4v o[4][2];
#pragma unroll
    for (int i=0;i<4;i++)
#pragma unroll
      for (int j=0;j<2;j++) o[i][j] = (f4v)(0.0f);

#pragma unroll
    for (int p=0;p<4;p++){
      int s = t + p*256;
      gload16(Qg + (size_t)(bm + ((s>>2)&127))*3072 + (s>>9)*32 + (s&3)*8,
              Qs + (size_t)(w*64 + p*256)*8);
    }
    for (int bn=0; bn<=bm; bn+=128){
      __syncthreads();
#pragma unroll
      for (int p=0;p<4;p++){
        int s = t + p*256;
        gload16(Kg + (size_t)(bn + ((s>>2)&127))*3072 + (s>>9)*32 + (s&3)*8,
                Ks + (size_t)(w*64 + p*256)*8);
      }
#pragma unroll
      for (int p=0;p<4;p++){
        int s = t + p*256;                  // kt=s>>8, dl=(s>>2)&63, c8=s&3
        gload16(Vg + (size_t)((s>>2)&63)*512 + bn + (s>>8)*32 + (s&3)*8,
                Vs + (size_t)(w*64 + p*256)*8);
      }
      __syncthreads();
      f4v sacc[4][4];
#pragma unroll
      for (int i=0;i<4;i++)
#pragma unroll
        for (int j=0;j<4;j++) sacc[i][j] = (f4v)(0.0f);
#pragma unroll
      for (int ki=0; ki<2; ki++){
        bf8v af[4], bk[4];
#pragma unroll
        for (int i=0;i<4;i++) af[i] = *(const bf8v*)(Qs + ki*4096 + (wr*64+i*16+lr)*32 + kb*8);
#pragma unroll
        for (int j=0;j<4;j++) bk[j] = *(const bf8v*)(Ks + ki*4096 + (wc*64+j*16+lr)*32 + kb*8);
#pragma unroll
        for (int i=0;i<4;i++)
#pragma unroll
          for (int j=0;j<4;j++)
            sacc[i][j] = __builtin_amdgcn_mfma_f32_16x16x32_bf16(af[i], bk[j], sacc[i][j], 0,0,0);
      }
      const bool diag = (bn == bm);
#pragma unroll
      for (int i=0;i<4;i++)
#pragma unroll
      for (int j=0;j<4;j++)
#pragma unroll
      for (int r=0;r<4;r++){
        const int row = wr*64 + i*16 + kb*4 + r;
        const int col = wc*64 + j*16 + lr;
        float sv = siluf(sacc[i][j][r])*(1.0f/1024.0f);
        if (diag && row < col) sv = 0.0f;
        Ss[(col>>5)*4096 + row*32 + (col&31)] = __float2bfloat16(sv);
      }
      __syncthreads();
#pragma unroll
      for (int kt=0; kt<4; kt++){
        bf8v af[4], bv[2];
#pragma unroll
        for (int i=0;i<4;i++) af[i] = *(const bf8v*)(Ss + kt*4096 + (wr*64+i*16+lr)*32 + kb*8);
#pragma unroll
        for (int j=0;j<2;j++) bv[j] = *(const bf8v*)(Vs + kt*2048 + (wc*32+j*16+lr)*32 + kb*8);
#pragma unroll
        for (int i=0;i<4;i++)
#pragma unroll
          for (int j=0;j<2;j++)
            o[i][j] = __builtin_amdgcn_mfma_f32_16x16x32_bf16(af[i], bv[j], o[i][j], 0,0,0);
      }
    }
#pragma unroll
    for (int i=0;i<4;i++)
#pragma unroll
    for (int j=0;j<2;j++)
#pragma unroll
    for (int r=0;r<4;r++){
      const int row = bm + wr*64 + i*16 + kb*4 + r;
      const int col = wc*32 + j*16 + lr;
      comb[((size_t)b*512 + row)*1536 + h*192 + 128 + col] = __float2bfloat16(o[i][j][r]);
    }
  } else {
    // ---- pos/ts channels: {Apos, Ats[b]} @ V[b], causal K-truncation ----
    bf16* As = smem;            // [2][128][32] 16KB
    bf16* Bs = smem + 8192;     // 16KB
    f4v acc[4][4];
    const int id2 = id - 256;
    const int bm = (3-(id2 & 3))*128, bn = ((id2>>2)&3)*128;
    const int z = id2 >> 4, b = z>>1, ch = z&1;
    const bf16* A  = ch ? (Ats + (size_t)b*512*512) : Apos;
    const bf16* Bt = vT + (size_t)b*512*512;
    gemm_core128(A, 512, Bt, 512, bm + 128, As, Bs, acc, bm, bn, 0);
    EPI_LOOP( comb[((size_t)b*512 + row)*1536 + (col>>6)*192 + ch*64 + (col&63)]
                  = __float2bfloat16(v); )
  }
}

// parts[z] = ams @ W0 over K-slice z (no atomics)
__global__ __launch_bounds__(256) void k_gemm_w0_sk(const bf16* __restrict__ ams,
                                                    const bf16* __restrict__ W0T,
                                                    float* __restrict__ parts){
  __shared__ __align__(16) bf16 As[2*128*32];
  __shared__ __align__(16) bf16 Bs[2*128*32];
  f4v acc[4][4];
  const int bm = blockIdx.x*128, bn = blockIdx.y*128, k0 = blockIdx.z*384;
  gemm_core128(ams, 1536, W0T, 1536, 384, As, Bs, acc, bm, bn, k0);
  float* P = parts + (size_t)blockIdx.z*4096*512;
  EPI_LOOP( P[(size_t)row*512 + col] = v; )
}

// X = x + b0 + sum(parts); nX = rms(X)  (one row per 128-thr block)
__global__ __launch_bounds__(128) void k_reduce_w0_rms(const float* __restrict__ parts,
                                                       const float* __restrict__ x,
                                                       const float* __restrict__ b0,
                                                       float* __restrict__ X,
                                                       bf16* __restrict__ nX){
  __shared__ float sbuf[16];
  const size_t row = blockIdx.x;
  const int t = threadIdx.x;
  float4 s = ((const float4*)(x + row*512))[t];
  const float4 bv = ((const float4*)b0)[t];
  s.x += bv.x; s.y += bv.y; s.z += bv.z; s.w += bv.w;
#pragma unroll
  for (int p=0;p<4;p++){
    const float4 pv = ((const float4*)(parts + (size_t)p*4096*512 + row*512))[t];
    s.x += pv.x; s.y += pv.y; s.z += pv.z; s.w += pv.w;
  }
  ((float4*)(X + row*512))[t] = s;
  float ss = s.x*s.x + s.y*s.y + s.z*s.z + s.w*s.w;
#pragma unroll
  for (int o=32;o>0;o>>=1) ss += __shfl_down(ss, o);
  const int ln = t & 63, wv = t >> 6;
  if (ln==0) sbuf[wv] = ss;
  __syncthreads();
  if (t==0) sbuf[8] = rsqrtf((sbuf[0]+sbuf[1])*(1.0f/512.0f) + 1e-6f);
  __syncthreads();
  const float r = sbuf[8];
  s4v o; o[0]=bfs(s.x*r); o[1]=bfs(s.y*r); o[2]=bfs(s.z*r); o[3]=bfs(s.w*r);
  ((s4v*)(nX + row*512))[t] = o;
}

// X1 = silu(nX@W1) * (nX@W3) — fused dual GEMM, BK=64
__global__ __launch_bounds__(256) void k_gemm_w13f(const bf16* __restrict__ nX,
                                                   const bf16* __restrict__ W1T,
                                                   const bf16* __restrict__ W3T,
                                                   bf16* __restrict__ X1){
  __shared__ __align__(16) bf16 As[2*128*32];
  __shared__ __align__(16) bf16 Bs1[2*64*32];
  __shared__ __align__(16) bf16 Bs3[2*64*32];
  f4v a1[4][2], a3[4][2];
  const int bm = blockIdx.x*128, bn = blockIdx.y*64;
  const int t = threadIdx.x, w = t>>6, l = t&63;
  const int wr = w>>1, wc = w&1, lr = l&15, kb = l>>4;
#pragma unroll
  for (int i=0;i<4;i++)
#pragma unroll
    for (int j=0;j<2;j++){ a1[i][j] = (f4v)(0.0f); a3[i][j] = (f4v)(0.0f); }

  for (int kt=0; kt<512; kt+=64){
    __syncthreads();
#pragma unroll
    for (int s=0;s<2;s++){
#pragma unroll
      for (int i=0;i<2;i++){
        int lin = t + i*256;
        gload16(nX + (size_t)(bm + (lin>>2))*512 + kt + s*32 + (lin&3)*8,
                As + s*4096 + (size_t)(w*64 + i*256)*8);
      }
      gload16(W1T + (size_t)(bn + (t>>2))*512 + kt + s*32 + (t&3)*8, Bs1 + s*2048 + (size_t)(w*64)*8);
      gload16(W3T + (size_t)(bn + (t>>2))*512 + kt + s*32 + (t&3)*8, Bs3 + s*2048 + (size_t)(w*64)*8);
    }
    __syncthreads();
#pragma unroll
    for (int s=0;s<2;s++){
      bf8v af[4], b1[2], b3[2];
#pragma unroll
      for (int i=0;i<4;i++) af[i] = *(const bf8v*)(As + s*4096 + (wr*64 + i*16 + lr)*32 + kb*8);
#pragma unroll
      for (int j=0;j<2;j++){ b1[j] = *(const bf8v*)(Bs1 + s*2048 + (wc*32 + j*16 + lr)*32 + kb*8);
                             b3[j] = *(const bf8v*)(Bs3 + s*2048 + (wc*32 + j*16 + lr)*32 + kb*8); }
#pragma unroll
      for (int i=0;i<4;i++)
#pragma unroll
        for (int j=0;j<2;j++){
          a1[i][j] = __builtin_amdgcn_mfma_f32_16x16x32_bf16(af[i], b1[j], a1[i][j], 0,0,0);
          a3[i][j] = __builtin_amdgcn_mfma_f32_16x16x32_bf16(af[i], b3[j], a3[i][j], 0,0,0);
        }
    }
  }
#pragma unroll
  for (int i=0;i<4;i++)
#pragma unroll
  for (int j=0;j<2;j++)
#pragma unroll
  for (int r=0;r<4;r++){
    const int row = bm + wr*64 + i*16 + kb*4 + r;
    const int col = bn + wc*32 + j*16 + lr;
    X1[(size_t)row*2048 + col] = __float2bfloat16(siluf(a1[i][j][r]) * a3[i][j][r]);
  }
}

// parts[z] = X1 @ W2 over K-slice z (no atomics)
__global__ __launch_bounds__(256) void k_gemm_w2_sk(const bf16* __restrict__ X1,
                                                    const bf16* __restrict__ W2T,
                                                    float* __restrict__ parts){
  __shared__ __align__(16) bf16 As[2*128*32];
  __shared__ __align__(16) bf16 Bs[2*128*32];
  f4v acc[4][4];
  const int bm = blockIdx.x*128, bn = blockIdx.y*128, k0 = blockIdx.z*512;
  gemm_core128(X1, 2048, W2T, 2048, 512, As, Bs, acc, bm, bn, k0);
  float* P = parts + (size_t)blockIdx.z*4096*512;
  EPI_LOOP( P[(size_t)row*512 + col] = v; )
}

// out += sum(parts[0..3])
__global__ __launch_bounds__(256) void k_reduce_w2(const float* __restrict__ parts,
                                                   float* __restrict__ out){
  const int i = blockIdx.x*256 + threadIdx.x;
  float4 s = ((const float4*)out)[i];
#pragma unroll
  for (int p=0;p<4;p++){
    const float4 pv = ((const float4*)(parts + (size_t)p*4096*512))[i];
    s.x += pv.x; s.y += pv.y; s.z += pv.z; s.w += pv.w;
  }
  ((float4*)out)[i] = s;
}

// ---------------- elementwise ----------------

// ams = u * rms(comb); one row per 192-thread block, short8/thread
__global__ __launch_bounds__(192) void k_rms_mul_u(const bf16* __restrict__ comb,
                                                   const bf16* __restrict__ mm,
                                                   bf16* __restrict__ ams){
  __shared__ float sbuf[16];
  const size_t rb = (size_t)blockIdx.x;
  const s8v cv = ((const s8v*)(comb + rb*1536))[threadIdx.x];
  float cf[8]; float ss = 0.f;
#pragma unroll
  for (int j=0;j<8;j++){ cf[j] = b2f(cv[j]); ss += cf[j]*cf[j]; }
#pragma unroll
  for (int o=32;o>0;o>>=1) ss += __shfl_down(ss, o);
  const int ln = threadIdx.x & 63, wv = threadIdx.x >> 6;
  if (ln==0) sbuf[wv] = ss;
  __syncthreads();
  if (threadIdx.x==0) sbuf[8] = rsqrtf((sbuf[0]+sbuf[1]+sbuf[2])*(1.0f/1536.0f) + 1e-6f);
  __syncthreads();
  const float r = sbuf[8];
  const s8v uv = ((const s8v*)(mm + rb*3072))[threadIdx.x];
  s8v o;
#pragma unroll
  for (int j=0;j<8;j++) o[j] = bfs(b2f(uv[j]) * cf[j] * r);
  ((s8v*)(ams + rb*1536))[threadIdx.x] = o;
}

// ---------------- launcher ----------------

extern "C" void kernel_launch(void* const* d_in, const int* in_sizes, int n_in,
                              void* d_out, int out_size, void* d_ws, size_t ws_size,
                              hipStream_t stream) {
  const float* x     = (const float*)d_in[0];
  const int*   ts    = (const int*)d_in[2];
  const float* uvqk  = (const float*)d_in[4];
  const float* pos_w = (const float*)d_in[5];
  const float* ts_w  = (const float*)d_in[6];
  const float* W0    = (const float*)d_in[7];
  const float* b0    = (const float*)d_in[8];
  const float* W1    = (const float*)d_in[9];
  const float* W2    = (const float*)d_in[10];
  const float* W3    = (const float*)d_in[11];
  float* out = (float*)d_out;          // X mid-pipeline, final result at end

  char* w = (char*)d_ws;
  auto alloc = [&](size_t bytes){ char* p = w; w += (bytes + 255) & ~(size_t)255; return p; };
  bf16*  xn    = (bf16*)alloc((size_t)4096*512*2);
  bf16*  uvqkT = (bf16*)alloc((size_t)3072*512*2);
  bf16*  W0T   = (bf16*)alloc((size_t)512*1536*2);
  bf16*  W13T  = (bf16*)alloc((size_t)4096*512*2);
  bf16*  W2T   = (bf16*)alloc((size_t)512*2048*2);
  bf16*  mm    = (bf16*)alloc((size_t)4096*3072*2);
  bf16*  vT    = (bf16*)alloc((size_t)8*512*512*2);
  bf16*  Apos  = (bf16*)alloc((size_t)512*512*2);
  bf16*  Ats   = (bf16*)alloc((size_t)8*512*512*2);
  bf16*  X1    = (bf16*)alloc((size_t)4096*2048*2);
  bf16*  comb  = (bf16*)alloc((size_t)4096*1536*2);
  bf16*  ams   = (bf16*)alloc((size_t)4096*1536*2);
  bf16*  nX    = (bf16*)alloc((size_t)4096*512*2);
  float* parts = (float*)alloc((size_t)4*4096*512*4);  // split-K partials (w0 then w2)

  // 1. minimal prep: uvqk transpose + input rmsnorm (gemm1's inputs)
  k_pre<<<5632, 256, 0, stream>>>(x, uvqk, xn, uvqkT);
  // 2. gemm1 + (concurrent) late weight transposes + bias matrices
  k_gemm1x<<<13824, 256, 0, stream>>>(xn, uvqkT, ts, pos_w, ts_w, W0, W1, W3, W2,
                                      mm, vT, W0T, W13T, W2T, Apos, Ats);
  // 3. merged attention: lat (flash-fused) + pos/ts channels
  k_attn<<<512, 256, 0, stream>>>(mm, vT, Apos, Ats, comb);
  // 4. ams = u * rms(comb)
  k_rms_mul_u<<<4096, 192, 0, stream>>>(comb, mm, ams);
  // 5. split-K x4 partials; then X = x+b0+sum, nX = rms(X) fused
  k_gemm_w0_sk<<<dim3(32, 4, 4), 256, 0, stream>>>(ams, W0T, parts);
  k_reduce_w0_rms<<<4096, 128, 0, stream>>>(parts, x, b0, out, nX);
  // 6. X1 = silu(nX@W1) * (nX@W3)
  k_gemm_w13f<<<dim3(32, 32), 256, 0, stream>>>(nX, W13T, W13T + (size_t)2048*512, X1);
  // 7. split-K x4 partials, then out += sum(parts)
  k_gemm_w2_sk<<<dim3(32, 4, 4), 256, 0, stream>>>(X1, W2T, parts);
  k_reduce_w2<<<2048, 256, 0, stream>>>(parts, out);
}

// Round 16
// 150.762 us; speedup vs baseline: 1.0535x; 1.0535x over previous
//
#include <hip/hip_runtime.h>
#include <hip/hip_bf16.h>
#include <cstdint>
#include <cstddef>

typedef __hip_bfloat16 bf16;
typedef __attribute__((ext_vector_type(8))) short bf8v;   // 8 bf16 MFMA A/B frag
typedef __attribute__((ext_vector_type(4))) float f4v;    // MFMA C/D frag
typedef __attribute__((ext_vector_type(4))) short s4v;
typedef __attribute__((ext_vector_type(8))) short s8v;

#define DEV static __device__ __forceinline__

DEV float siluf(float v){ return v / (1.0f + __expf(-v)); }
DEV short bfs(float f){ bf16 h = __float2bfloat16(f); return __builtin_bit_cast(short, h); }
DEV float b2f(short s){ return __builtin_bit_cast(float, (unsigned)((unsigned short)s) << 16); }

DEV void gload16(const bf16* g, bf16* l){
  __builtin_amdgcn_global_load_lds((const __attribute__((address_space(1))) void*)g,
                                   (__attribute__((address_space(3))) void*)l, 16, 0, 0);
}

// ---------------- bt-GEMM core, 2-phase double-buffered BK=32.
// As/Bs: [2][128][32] bf16 (two 8KB halves each). Prefetch tile t+1 while
// computing tile t; one __syncthreads per 32-K-step (drain lands AFTER MFMA).
// MFMA accumulation order identical to the single-buffered version (bit-identical).
DEV void gemm_core128(const bf16* __restrict__ A, int lda,
                      const bf16* __restrict__ Bt, int ldb,
                      int K, bf16* As, bf16* Bs, f4v (&acc)[4][4],
                      int bm, int bn, int k0)
{
  const int t = threadIdx.x, w = t>>6, l = t&63;
  const int wr = w>>1, wc = w&1, lr = l&15, kb = l>>4;
#pragma unroll
  for (int i=0;i<4;i++)
#pragma unroll
    for (int j=0;j<4;j++) acc[i][j] = (f4v)(0.0f);

  auto STAGE = [&](int half, int kt){
#pragma unroll
    for (int i=0;i<2;i++){
      int lin = t + i*256;
      gload16(A + (size_t)(bm + (lin>>2))*lda + kt + (lin&3)*8,
              As + half*4096 + (size_t)(w*64 + i*256)*8);
    }
#pragma unroll
    for (int i=0;i<2;i++){
      int lin = t + i*256;
      gload16(Bt + (size_t)(bn + (lin>>2))*ldb + kt + (lin&3)*8,
              Bs + half*4096 + (size_t)(w*64 + i*256)*8);
    }
  };
  auto COMPUTE = [&](int half){
    bf8v af[4], bfr[4];
#pragma unroll
    for (int i=0;i<4;i++) af[i]  = *(const bf8v*)(As + half*4096 + (wr*64 + i*16 + lr)*32 + kb*8);
#pragma unroll
    for (int j=0;j<4;j++) bfr[j] = *(const bf8v*)(Bs + half*4096 + (wc*64 + j*16 + lr)*32 + kb*8);
#pragma unroll
    for (int i=0;i<4;i++)
#pragma unroll
      for (int j=0;j<4;j++)
        acc[i][j] = __builtin_amdgcn_mfma_f32_16x16x32_bf16(af[i], bfr[j], acc[i][j], 0,0,0);
  };

  STAGE(0, k0);
  __syncthreads();                 // tile 0 ready
  int cur = 0;
  for (int kt = k0+32; kt < k0+K; kt += 32){
    STAGE(cur^1, kt);              // issue next tile's loads (fly under MFMA)
    COMPUTE(cur);
    __syncthreads();               // drains prefetch; all waves done reading cur
    cur ^= 1;
  }
  COMPUTE(cur);                    // last tile
}

#define EPI_LOOP(...) { \
  const int t_=threadIdx.x, w_=t_>>6, l_=t_&63; \
  const int wr_=w_>>1, wc_=w_&1, lr_=l_&15, kb_=l_>>4; \
  _Pragma("unroll") for (int i_=0;i_<4;i_++) \
  _Pragma("unroll") for (int j_=0;j_<4;j_++) \
  _Pragma("unroll") for (int r_=0;r_<4;r_++){ \
    const int row = bm + wr_*64 + i_*16 + kb_*4 + r_; \
    const int col = bn + wc_*64 + j_*16 + lr_; \
    float v = acc[i_][j_][r_]; \
    __VA_ARGS__; \
  } }

// ---------------- GEMM kernels ----------------

// mm = silu(xn @ uvqk); v-columns (1536..2048) are written transposed into vT instead.
__global__ __launch_bounds__(256) void k_gemm1(const bf16* __restrict__ xn,
                                               const bf16* __restrict__ uvqkT,
                                               bf16* __restrict__ mm,
                                               bf16* __restrict__ vT){
  __shared__ __align__(16) bf16 As[2*128*32];
  __shared__ __align__(16) bf16 Bs[2*128*32];
  f4v acc[4][4];
  const int bm = blockIdx.x*128, bn = blockIdx.y*128;
  gemm_core128(xn, 512, uvqkT, 512, 512, As, Bs, acc, bm, bn, 0);
  const int t=threadIdx.x, w=t>>6, l=t&63;
  const int wr=w>>1, wc=w&1, lr=l&15, kb=l>>4;
  const bool isv = (bn >= 1536) && (bn < 2048);
#pragma unroll
  for (int i=0;i<4;i++)
#pragma unroll
  for (int j=0;j<4;j++){
    const int row0 = bm + wr*64 + i*16 + kb*4;
    const int col  = bn + wc*64 + j*16 + lr;
    if (!isv){
#pragma unroll
      for (int r=0;r<4;r++)
        mm[(size_t)(row0+r)*3072 + col] = __float2bfloat16(siluf(acc[i][j][r]));
    } else {
      s4v p;
#pragma unroll
      for (int r=0;r<4;r++) p[r] = bfs(siluf(acc[i][j][r]));
      const int b = row0 >> 9, m = row0 & 511;
      *(s4v*)(vT + ((size_t)b*512 + (col-1536))*512 + m) = p;   // vT[b][vcol][m]
    }
  }
}

// merged attention: ids 0..255 = fused lat channel (flash-style), 256..511 = pos/ts PV GEMMs.
__global__ __launch_bounds__(256) void k_attn(const bf16* __restrict__ mm,
                                              const bf16* __restrict__ vT,
                                              const bf16* __restrict__ Apos,
                                              const bf16* __restrict__ Ats,
                                              bf16* __restrict__ comb){
  __shared__ __align__(16) bf16 smem[40960];   // 80 KB carved per branch
  const int id = blockIdx.x;
  const int t = threadIdx.x, w = t>>6, l = t&63;
  const int wr = w>>1, wc = w&1, lr = l&15, kb = l>>4;

  if (id < 256){
    // ---- lat channel: O[128x64] = sum_bn tril(silu(Q Kt)/N) @ V ----
    bf16* Qs = smem;            // [2][128][32] 16KB
    bf16* Ks = smem + 8192;     // 16KB
    bf16* Vs = smem + 16384;    // [4][64][32] 16KB
    bf16* Ss = smem + 24576;    // [4][128][32] 32KB
    const int bm = (id & 3)*128;
    const int z = id >> 2, b = z>>3, h = z&7;
    const bf16* Qg = mm + (size_t)b*512*3072 + 2048 + h*64;
    const bf16* Kg = mm + (size_t)b*512*3072 + 2560 + h*64;
    const bf16* Vg = vT + ((size_t)b*512 + h*64)*512;
    f4v o[4][2];
#pragma unroll
    for (int i=0;i<4;i++)
#pragma unroll
      for (int j=0;j<2;j++) o[i][j] = (f4v)(0.0f);

#pragma unroll
    for (int p=0;p<4;p++){
      int s = t + p*256;
      gload16(Qg + (size_t)(bm + ((s>>2)&127))*3072 + (s>>9)*32 + (s&3)*8,
              Qs + (size_t)(w*64 + p*256)*8);
    }
    for (int bn=0; bn<=bm; bn+=128){
      __syncthreads();
#pragma unroll
      for (int p=0;p<4;p++){
        int s = t + p*256;
        gload16(Kg + (size_t)(bn + ((s>>2)&127))*3072 + (s>>9)*32 + (s&3)*8,
                Ks + (size_t)(w*64 + p*256)*8);
      }
#pragma unroll
      for (int p=0;p<4;p++){
        int s = t + p*256;                  // kt=s>>8, dl=(s>>2)&63, c8=s&3
        gload16(Vg + (size_t)((s>>2)&63)*512 + bn + (s>>8)*32 + (s&3)*8,
                Vs + (size_t)(w*64 + p*256)*8);
      }
      __syncthreads();
      f4v sacc[4][4];
#pragma unroll
      for (int i=0;i<4;i++)
#pragma unroll
        for (int j=0;j<4;j++) sacc[i][j] = (f4v)(0.0f);
#pragma unroll
      for (int ki=0; ki<2; ki++){
        bf8v af[4], bk[4];
#pragma unroll
        for (int i=0;i<4;i++) af[i] = *(const bf8v*)(Qs + ki*4096 + (wr*64+i*16+lr)*32 + kb*8);
#pragma unroll
        for (int j=0;j<4;j++) bk[j] = *(const bf8v*)(Ks + ki*4096 + (wc*64+j*16+lr)*32 + kb*8);
#pragma unroll
        for (int i=0;i<4;i++)
#pragma unroll
          for (int j=0;j<4;j++)
            sacc[i][j] = __builtin_amdgcn_mfma_f32_16x16x32_bf16(af[i], bk[j], sacc[i][j], 0,0,0);
      }
      const bool diag = (bn == bm);
#pragma unroll
      for (int i=0;i<4;i++)
#pragma unroll
      for (int j=0;j<4;j++)
#pragma unroll
      for (int r=0;r<4;r++){
        const int row = wr*64 + i*16 + kb*4 + r;
        const int col = wc*64 + j*16 + lr;
        float sv = siluf(sacc[i][j][r])*(1.0f/1024.0f);
        if (diag && row < col) sv = 0.0f;
        Ss[(col>>5)*4096 + row*32 + (col&31)] = __float2bfloat16(sv);
      }
      __syncthreads();
#pragma unroll
      for (int kt=0; kt<4; kt++){
        bf8v af[4], bv[2];
#pragma unroll
        for (int i=0;i<4;i++) af[i] = *(const bf8v*)(Ss + kt*4096 + (wr*64+i*16+lr)*32 + kb*8);
#pragma unroll
        for (int j=0;j<2;j++) bv[j] = *(const bf8v*)(Vs + kt*2048 + (wc*32+j*16+lr)*32 + kb*8);
#pragma unroll
        for (int i=0;i<4;i++)
#pragma unroll
          for (int j=0;j<2;j++)
            o[i][j] = __builtin_amdgcn_mfma_f32_16x16x32_bf16(af[i], bv[j], o[i][j], 0,0,0);
      }
    }
#pragma unroll
    for (int i=0;i<4;i++)
#pragma unroll
    for (int j=0;j<2;j++)
#pragma unroll
    for (int r=0;r<4;r++){
      const int row = bm + wr*64 + i*16 + kb*4 + r;
      const int col = wc*32 + j*16 + lr;
      comb[((size_t)b*512 + row)*1536 + h*192 + 128 + col] = __float2bfloat16(o[i][j][r]);
    }
  } else {
    // ---- pos/ts channels: {Apos, Ats[b]} @ V[b], causal K-truncation ----
    bf16* As = smem;            // [2][128][32] x2 halves = 16KB
    bf16* Bs = smem + 8192;     // 16KB
    f4v acc[4][4];
    const int id2 = id - 256;
    const int bm = (id2 & 3)*128, bn = ((id2>>2)&3)*128;
    const int z = id2 >> 4, b = z>>1, ch = z&1;
    const bf16* A  = ch ? (Ats + (size_t)b*512*512) : Apos;
    const bf16* Bt = vT + (size_t)b*512*512;
    gemm_core128(A, 512, Bt, 512, bm + 128, As, Bs, acc, bm, bn, 0);
    EPI_LOOP( comb[((size_t)b*512 + row)*1536 + (col>>6)*192 + ch*64 + (col&63)]
                  = __float2bfloat16(v); )
  }
}

// parts[z] = ams @ W0 over K-slice z (no atomics)
__global__ __launch_bounds__(256) void k_gemm_w0_sk(const bf16* __restrict__ ams,
                                                    const bf16* __restrict__ W0T,
                                                    float* __restrict__ parts){
  __shared__ __align__(16) bf16 As[2*128*32];
  __shared__ __align__(16) bf16 Bs[2*128*32];
  f4v acc[4][4];
  const int bm = blockIdx.x*128, bn = blockIdx.y*128, k0 = blockIdx.z*384;
  gemm_core128(ams, 1536, W0T, 1536, 384, As, Bs, acc, bm, bn, k0);
  float* P = parts + (size_t)blockIdx.z*4096*512;
  EPI_LOOP( P[(size_t)row*512 + col] = v; )
}

// X = x + b0 + sum(parts); nX = rms(X)  (one row per 128-thr block)
__global__ __launch_bounds__(128) void k_reduce_w0_rms(const float* __restrict__ parts,
                                                       const float* __restrict__ x,
                                                       const float* __restrict__ b0,
                                                       float* __restrict__ X,
                                                       bf16* __restrict__ nX){
  __shared__ float sbuf[16];
  const size_t row = blockIdx.x;
  const int t = threadIdx.x;
  float4 s = ((const float4*)(x + row*512))[t];
  const float4 bv = ((const float4*)b0)[t];
  s.x += bv.x; s.y += bv.y; s.z += bv.z; s.w += bv.w;
#pragma unroll
  for (int p=0;p<4;p++){
    const float4 pv = ((const float4*)(parts + (size_t)p*4096*512 + row*512))[t];
    s.x += pv.x; s.y += pv.y; s.z += pv.z; s.w += pv.w;
  }
  ((float4*)(X + row*512))[t] = s;
  float ss = s.x*s.x + s.y*s.y + s.z*s.z + s.w*s.w;
#pragma unroll
  for (int o=32;o>0;o>>=1) ss += __shfl_down(ss, o);
  const int ln = t & 63, wv = t >> 6;
  if (ln==0) sbuf[wv] = ss;
  __syncthreads();
  if (t==0) sbuf[8] = rsqrtf((sbuf[0]+sbuf[1])*(1.0f/512.0f) + 1e-6f);
  __syncthreads();
  const float r = sbuf[8];
  s4v o; o[0]=bfs(s.x*r); o[1]=bfs(s.y*r); o[2]=bfs(s.z*r); o[3]=bfs(s.w*r);
  ((s4v*)(nX + row*512))[t] = o;
}

// X1 = silu(nX@W1) * (nX@W3) — fused dual GEMM, 2-phase double-buffered BK=32
__global__ __launch_bounds__(256) void k_gemm_w13f(const bf16* __restrict__ nX,
                                                   const bf16* __restrict__ W1T,
                                                   const bf16* __restrict__ W3T,
                                                   bf16* __restrict__ X1){
  __shared__ __align__(16) bf16 As[2*128*32];
  __shared__ __align__(16) bf16 Bs1[2*64*32];
  __shared__ __align__(16) bf16 Bs3[2*64*32];
  f4v a1[4][2], a3[4][2];
  const int bm = blockIdx.x*128, bn = blockIdx.y*64;
  const int t = threadIdx.x, w = t>>6, l = t&63;
  const int wr = w>>1, wc = w&1, lr = l&15, kb = l>>4;
#pragma unroll
  for (int i=0;i<4;i++)
#pragma unroll
    for (int j=0;j<2;j++){ a1[i][j] = (f4v)(0.0f); a3[i][j] = (f4v)(0.0f); }

  auto STAGE = [&](int half, int kt){
#pragma unroll
    for (int i=0;i<2;i++){
      int lin = t + i*256;
      gload16(nX + (size_t)(bm + (lin>>2))*512 + kt + (lin&3)*8,
              As + half*4096 + (size_t)(w*64 + i*256)*8);
    }
    gload16(W1T + (size_t)(bn + (t>>2))*512 + kt + (t&3)*8, Bs1 + half*2048 + (size_t)(w*64)*8);
    gload16(W3T + (size_t)(bn + (t>>2))*512 + kt + (t&3)*8, Bs3 + half*2048 + (size_t)(w*64)*8);
  };
  auto COMPUTE = [&](int half){
    bf8v af[4], b1[2], b3[2];
#pragma unroll
    for (int i=0;i<4;i++) af[i] = *(const bf8v*)(As + half*4096 + (wr*64 + i*16 + lr)*32 + kb*8);
#pragma unroll
    for (int j=0;j<2;j++){ b1[j] = *(const bf8v*)(Bs1 + half*2048 + (wc*32 + j*16 + lr)*32 + kb*8);
                           b3[j] = *(const bf8v*)(Bs3 + half*2048 + (wc*32 + j*16 + lr)*32 + kb*8); }
#pragma unroll
    for (int i=0;i<4;i++)
#pragma unroll
      for (int j=0;j<2;j++){
        a1[i][j] = __builtin_amdgcn_mfma_f32_16x16x32_bf16(af[i], b1[j], a1[i][j], 0,0,0);
        a3[i][j] = __builtin_amdgcn_mfma_f32_16x16x32_bf16(af[i], b3[j], a3[i][j], 0,0,0);
      }
  };

  STAGE(0, 0);
  __syncthreads();
  int cur = 0;
  for (int kt = 32; kt < 512; kt += 32){
    STAGE(cur^1, kt);
    COMPUTE(cur);
    __syncthreads();
    cur ^= 1;
  }
  COMPUTE(cur);

#pragma unroll
  for (int i=0;i<4;i++)
#pragma unroll
  for (int j=0;j<2;j++)
#pragma unroll
  for (int r=0;r<4;r++){
    const int row = bm + wr*64 + i*16 + kb*4 + r;
    const int col = bn + wc*32 + j*16 + lr;
    X1[(size_t)row*2048 + col] = __float2bfloat16(siluf(a1[i][j][r]) * a3[i][j][r]);
  }
}

// parts[z] = X1 @ W2 over K-slice z (no atomics)
__global__ __launch_bounds__(256) void k_gemm_w2_sk(const bf16* __restrict__ X1,
                                                    const bf16* __restrict__ W2T,
                                                    float* __restrict__ parts){
  __shared__ __align__(16) bf16 As[2*128*32];
  __shared__ __align__(16) bf16 Bs[2*128*32];
  f4v acc[4][4];
  const int bm = blockIdx.x*128, bn = blockIdx.y*128, k0 = blockIdx.z*512;
  gemm_core128(X1, 2048, W2T, 2048, 512, As, Bs, acc, bm, bn, k0);
  float* P = parts + (size_t)blockIdx.z*4096*512;
  EPI_LOOP( P[(size_t)row*512 + col] = v; )
}

// out += sum(parts[0..3])
__global__ __launch_bounds__(256) void k_reduce_w2(const float* __restrict__ parts,
                                                   float* __restrict__ out){
  const int i = blockIdx.x*256 + threadIdx.x;
  float4 s = ((const float4*)out)[i];
#pragma unroll
  for (int p=0;p<4;p++){
    const float4 pv = ((const float4*)(parts + (size_t)p*4096*512))[i];
    s.x += pv.x; s.y += pv.y; s.z += pv.z; s.w += pv.w;
  }
  ((float4*)out)[i] = s;
}

// ---------------- elementwise / prep ----------------

// ams = u * rms(comb); one row per 192-thread block, short8/thread
__global__ __launch_bounds__(192) void k_rms_mul_u(const bf16* __restrict__ comb,
                                                   const bf16* __restrict__ mm,
                                                   bf16* __restrict__ ams){
  __shared__ float sbuf[16];
  const size_t rb = (size_t)blockIdx.x;
  const s8v cv = ((const s8v*)(comb + rb*1536))[threadIdx.x];
  float cf[8]; float ss = 0.f;
#pragma unroll
  for (int j=0;j<8;j++){ cf[j] = b2f(cv[j]); ss += cf[j]*cf[j]; }
#pragma unroll
  for (int o=32;o>0;o>>=1) ss += __shfl_down(ss, o);
  const int ln = threadIdx.x & 63, wv = threadIdx.x >> 6;
  if (ln==0) sbuf[wv] = ss;
  __syncthreads();
  if (threadIdx.x==0) sbuf[8] = rsqrtf((sbuf[0]+sbuf[1]+sbuf[2])*(1.0f/1536.0f) + 1e-6f);
  __syncthreads();
  const float r = sbuf[8];
  const s8v uv = ((const s8v*)(mm + rb*3072))[threadIdx.x];
  s8v o;
#pragma unroll
  for (int j=0;j<8;j++) o[j] = bfs(b2f(uv[j]) * cf[j] * r);
  ((s8v*)(ams + rb*1536))[threadIdx.x] = o;
}

// one kernel: 5 weight transposes (0..5375) + bias matrices (5376..14591) + input rmsnorm (14592..18687)
__global__ __launch_bounds__(256) void k_prep(
    const float* __restrict__ x,    const int* __restrict__ ts,
    const float* __restrict__ pos_w,const float* __restrict__ ts_w,
    const float* __restrict__ uvqk, const float* __restrict__ W0,
    const float* __restrict__ W1,   const float* __restrict__ W3,
    const float* __restrict__ W2,
    bf16* __restrict__ xn,
    bf16* __restrict__ uvqkT, bf16* __restrict__ W0T,
    bf16* __restrict__ W13T,  bf16* __restrict__ W2T,
    bf16* __restrict__ Apos,  bf16* __restrict__ Ats){
  __shared__ float tile[32][33];
  __shared__ float sbuf[16];
  int id = blockIdx.x;
  if (id < 5376){
    const float* src; bf16* dst; int R, C;
    if      (id < 1536){            src=uvqk; dst=uvqkT;                  R=512;  C=3072; }
    else if (id < 2304){ id-=1536;  src=W0;   dst=W0T;                    R=1536; C=512;  }
    else if (id < 3328){ id-=2304;  src=W1;   dst=W13T;                   R=512;  C=2048; }
    else if (id < 4352){ id-=3328;  src=W3;   dst=W13T+(size_t)2048*512;  R=512;  C=2048; }
    else               { id-=4352;  src=W2;   dst=W2T;                    R=2048; C=512;  }
    const int nbx = C >> 5;
    const int c0 = (id % nbx)*32, r0 = (id / nbx)*32;
    const int tx = threadIdx.x & 31, ty = threadIdx.x >> 5;
#pragma unroll
    for (int i=0;i<32;i+=8) tile[ty+i][tx] = src[(size_t)(r0+ty+i)*C + (c0+tx)];
    __syncthreads();
#pragma unroll
    for (int i=0;i<32;i+=8) dst[(size_t)(c0+ty+i)*R + (r0+tx)] = __float2bfloat16(tile[tx][ty+i]);
  } else if (id < 14592){
    int id2 = id - 5376;
    const int mblk = id2 & 1, n = (id2>>1)&511, z = id2>>10;
    if (mblk*256 > n) return;                 // above diagonal: zero & unread
    const int m = mblk*256 + threadIdx.x;
    if (z == 0){
      float v = (n >= m) ? pos_w[n - m + 1023] : 0.f;
      Apos[(size_t)n*512 + m] = __float2bfloat16(v);
    } else {
      const int b = z-1;
      int dt = ts[b*1024 + n] - ts[b*1024 + m];
      float ad = (float)(dt < 0 ? -dt : dt);
      int bucket = (int)floorf(logf(ad + 1.0f));
      bucket = bucket < 0 ? 0 : (bucket > 127 ? 127 : bucket);
      float v = (n >= m) ? ts_w[bucket] : 0.f;
      Ats[((size_t)b*512 + n)*512 + m] = __float2bfloat16(v);
    }
  } else {
    // input rmsnorm — bit-identical to round-9 k_rmsnorm (128 active threads, float4)
    const size_t row = id - 14592;
    const int t = threadIdx.x;
    if (t >= 128) return;                     // waves 2,3 exit (wave-uniform)
    const float4 v = ((const float4*)(x + row*512))[t];
    float ss = v.x*v.x + v.y*v.y + v.z*v.z + v.w*v.w;
#pragma unroll
    for (int o=32;o>0;o>>=1) ss += __shfl_down(ss, o);
    const int ln = t & 63, wv = t >> 6;
    if (ln==0) sbuf[wv] = ss;
    __syncthreads();
    if (t==0) sbuf[8] = rsqrtf((sbuf[0]+sbuf[1])*(1.0f/512.0f) + 1e-6f);
    __syncthreads();
    const float r = sbuf[8];
    s4v o; o[0]=bfs(v.x*r); o[1]=bfs(v.y*r); o[2]=bfs(v.z*r); o[3]=bfs(v.w*r);
    ((s4v*)(xn + row*512))[t] = o;
  }
}

// ---------------- launcher ----------------

extern "C" void kernel_launch(void* const* d_in, const int* in_sizes, int n_in,
                              void* d_out, int out_size, void* d_ws, size_t ws_size,
                              hipStream_t stream) {
  const float* x     = (const float*)d_in[0];
  const int*   ts    = (const int*)d_in[2];
  const float* uvqk  = (const float*)d_in[4];
  const float* pos_w = (const float*)d_in[5];
  const float* ts_w  = (const float*)d_in[6];
  const float* W0    = (const float*)d_in[7];
  const float* b0    = (const float*)d_in[8];
  const float* W1    = (const float*)d_in[9];
  const float* W2    = (const float*)d_in[10];
  const float* W3    = (const float*)d_in[11];
  float* out = (float*)d_out;          // X mid-pipeline, final result at end

  char* w = (char*)d_ws;
  auto alloc = [&](size_t bytes){ char* p = w; w += (bytes + 255) & ~(size_t)255; return p; };
  bf16*  xn    = (bf16*)alloc((size_t)4096*512*2);
  bf16*  uvqkT = (bf16*)alloc((size_t)3072*512*2);
  bf16*  W0T   = (bf16*)alloc((size_t)512*1536*2);
  bf16*  W13T  = (bf16*)alloc((size_t)4096*512*2);
  bf16*  W2T   = (bf16*)alloc((size_t)512*2048*2);
  bf16*  mm    = (bf16*)alloc((size_t)4096*3072*2);
  bf16*  vT    = (bf16*)alloc((size_t)8*512*512*2);
  bf16*  Apos  = (bf16*)alloc((size_t)512*512*2);
  bf16*  Ats   = (bf16*)alloc((size_t)8*512*512*2);
  bf16*  X1    = (bf16*)alloc((size_t)4096*2048*2);
  bf16*  comb  = (bf16*)alloc((size_t)4096*1536*2);
  bf16*  ams   = (bf16*)alloc((size_t)4096*1536*2);
  bf16*  nX    = (bf16*)alloc((size_t)4096*512*2);
  float* parts = (float*)alloc((size_t)4*4096*512*4);  // split-K partials (w0 then w2)

  // 1. all prep: weight transposes + bias matrices + input rmsnorm (one launch)
  k_prep<<<18688, 256, 0, stream>>>(x, ts, pos_w, ts_w, uvqk, W0, W1, W3, W2,
                                    xn, uvqkT, W0T, W13T, W2T, Apos, Ats);
  // 2. mm = silu(xn @ uvqk); v-cols go straight to vT (transposed)
  k_gemm1<<<dim3(32, 24), 256, 0, stream>>>(xn, uvqkT, mm, vT);
  // 3. merged attention: lat (flash-fused) + pos/ts channels
  k_attn<<<512, 256, 0, stream>>>(mm, vT, Apos, Ats, comb);
  // 4. ams = u * rms(comb)
  k_rms_mul_u<<<4096, 192, 0, stream>>>(comb, mm, ams);
  // 5. split-K x4 partials; then X = x+b0+sum, nX = rms(X) fused
  k_gemm_w0_sk<<<dim3(32, 4, 4), 256, 0, stream>>>(ams, W0T, parts);
  k_reduce_w0_rms<<<4096, 128, 0, stream>>>(parts, x, b0, out, nX);
  // 6. X1 = silu(nX@W1) * (nX@W3)   (grid (32,32): BN=64 tile over 2048 cols!)
  k_gemm_w13f<<<dim3(32, 32), 256, 0, stream>>>(nX, W13T, W13T + (size_t)2048*512, X1);
  // 7. split-K x4 partials, then out += sum(parts)
  k_gemm_w2_sk<<<dim3(32, 4, 4), 256, 0, stream>>>(X1, W2T, parts);
  k_reduce_w2<<<2048, 256, 0, stream>>>(parts, out);
}